// Round 12
// baseline (505.538 us; speedup 1.0000x reference)
//
#include <hip/hip_runtime.h>

#define BATCH 2048

// block-wide f32 sum; all threads get the result. red >= 32 floats.
__device__ __forceinline__ float blockReduceSumF(float v, float* red, int tid, int nwaves) {
  #pragma unroll
  for (int off = 32; off > 0; off >>= 1) v += __shfl_xor(v, off);
  __syncthreads();
  if ((tid & 63) == 0) red[tid >> 6] = v;
  __syncthreads();
  if (tid == 0) {
    float s = red[0];
    for (int i = 1; i < nwaves; i++) s += red[i];
    red[31] = s;
  }
  __syncthreads();
  return red[31];
}

// 4-wave (256-thread) group reduce; seg = 4-float LDS segment for this group.
// All 1024 threads of the block must call (uniform barriers).
__device__ __forceinline__ float groupReduce4w(float v, float* seg, int tj) {
  #pragma unroll
  for (int off = 32; off > 0; off >>= 1) v += __shfl_xor(v, off);
  __syncthreads();
  if ((tj & 63) == 0) seg[tj >> 6] = v;
  __syncthreads();
  return (seg[0] + seg[1]) + (seg[2] + seg[3]);
}

// ---------------- K1: conv1 + ternarize -> sign map + alpha1 (f32) — R11 verbatim ----
__global__ __launch_bounds__(512, 6) void k1_conv1(
    const float* __restrict__ x, const float* __restrict__ w1, const float* __restrict__ b1,
    signed char* __restrict__ s1full, float* __restrict__ alpha1) {
  __shared__ float xs[784];
  __shared__ float wsm[800];
  __shared__ float red[32];

  const int tid = threadIdx.x;
  const int smp = blockIdx.x;

  for (int j = tid; j < 784; j += 512) xs[j] = x[smp * 784 + j];
  for (int j = tid; j < 800; j += 512) wsm[j] = w1[j];
  __syncthreads();

  const int c = tid >> 4;
  const int g = tid & 15;
  const float bias = b1[c];
  const float* wc = &wsm[c * 25];

  float a[36];
  float asum = 0.0f;
  #pragma unroll
  for (int tt = 0; tt < 3; tt++) {
    const int t = g + (tt << 4);
    const int r = t >> 1;
    const int hx = (t & 1) * 12;
    float acc[12];
    #pragma unroll
    for (int i = 0; i < 12; i++) acc[i] = bias;
    #pragma unroll
    for (int ky = 0; ky < 5; ky++) {
      const float* xp = &xs[(r + ky) * 28 + hx];
      float xrow[16];
      *(float4*)&xrow[0]  = *(const float4*)&xp[0];
      *(float4*)&xrow[4]  = *(const float4*)&xp[4];
      *(float4*)&xrow[8]  = *(const float4*)&xp[8];
      *(float4*)&xrow[12] = *(const float4*)&xp[12];
      #pragma unroll
      for (int kx = 0; kx < 5; kx++) {
        const float w = wc[ky * 5 + kx];
        #pragma unroll
        for (int i = 0; i < 12; i++) acc[i] = fmaf(xrow[i + kx], w, acc[i]);
      }
    }
    #pragma unroll
    for (int i = 0; i < 12; i++) { a[tt * 12 + i] = acc[i]; asum += fabsf(acc[i]); }
  }

  float tot = blockReduceSumF(asum, red, tid, 8);
  float delta = (0.7f * tot) / 18432.0f;

  float msum = 0.0f, mcnt = 0.0f;
  #pragma unroll
  for (int i = 0; i < 36; i++) {
    float fa = fabsf(a[i]);
    if (fa > delta) { msum += fa; mcnt += 1.0f; }
  }
  msum = blockReduceSumF(msum, red, tid, 8);
  mcnt = blockReduceSumF(mcnt, red, tid, 8);
  if (tid == 0) alpha1[smp] = (mcnt > 0.0f) ? (msum / mcnt) : 0.0f;

  signed char* sp = s1full + (size_t)smp * 18432 + c * 576 + g * 12;
  #pragma unroll
  for (int tt = 0; tt < 3; tt++) {
    #pragma unroll
    for (int i = 0; i < 12; i++) {
      float v = a[tt * 12 + i];
      int sv = (v > delta) ? 1 : ((v < -delta) ? -1 : 0);
      sp[tt * 192 + i] = (signed char)sv;
    }
  }
}

// ---------------- K2: BN1+maxpool+relu, conv2, ternarize ----
// R12 change: weights staged through LDS in 2-cc chunks (coalesced global -> LDS,
// then 7x ds_read_b128 per thread) replacing 25 unaligned per-thread L2 loads per cc.
// FMA order and operand values are bitwise-identical to R11.
// LDS wlds layout: [c2][60] floats; cc-half at +0 / +28 (16B-aligned); 60-dword stride
// gives 2-way-max bank aliasing on the 16 distinct addresses per wave (free).
__global__ __launch_bounds__(256, 6) void k2_conv2(
    const signed char* __restrict__ s1full, const float* __restrict__ alpha1,
    const float* __restrict__ w2, const float* __restrict__ b2,
    const float* __restrict__ g1, const float* __restrict__ bt1,
    signed char* __restrict__ s2full, float* __restrict__ alpha2) {
  __shared__ float pooled[4608];
  __shared__ float wlds[3840];     // 64 * 60
  __shared__ float g1l[32], bt1l[32];
  __shared__ float red[32];

  const int tid = threadIdx.x;
  const int smp = blockIdx.x;
  const float BNINV = (float)(1.0 / sqrt(1.0 + 1e-5));

  if (tid < 32) { g1l[tid] = g1[tid] * BNINV; bt1l[tid] = bt1[tid]; }
  __syncthreads();

  const float a1 = alpha1[smp];
  for (int j = tid; j < 4608; j += 256) {
    int cc = j / 144;
    int r = j - cc * 144;
    int py = r / 12;
    int px = r - py * 12;
    const signed char* sp = s1full + (size_t)smp * 18432 + cc * 576 + (py * 2) * 24 + px * 2;
    float m = -1e30f;
    #pragma unroll
    for (int dy = 0; dy < 2; dy++)
      #pragma unroll
      for (int dx = 0; dx < 2; dx++) {
        float v = ((float)sp[dy * 24 + dx] * a1) * g1l[cc] + bt1l[cc];
        m = (v > m) ? v : m;
      }
    pooled[j] = (m > 0.0f) ? m : 0.0f;
  }

  const int c2 = tid >> 2;
  const int q = tid & 3;
  const int r0 = q << 1;
  const float bias = b2[c2];
  float acc0[8], acc1[8];
  #pragma unroll
  for (int i = 0; i < 8; i++) { acc0[i] = bias; acc1[i] = bias; }

  for (int cc0 = 0; cc0 < 32; cc0 += 2) {
    __syncthreads();  // prev-chunk readers done (also covers pooled on first iter)
    // stage 64 c2 x 2 cc x 25 weights; src runs of 50 contiguous floats per c2
    for (int i = tid; i < 3200; i += 256) {
      int c2i = i / 50;
      int r = i - c2i * 50;
      int dst = (r < 25) ? r : (r + 3);  // second half at +28
      wlds[c2i * 60 + dst] = w2[(c2i * 32 + cc0) * 25 + r];
    }
    __syncthreads();

    #pragma unroll
    for (int ccl = 0; ccl < 2; ccl++) {
      const float* wb = &wlds[c2 * 60 + ccl * 28];
      float wreg[28];
      *(float4*)&wreg[0]  = *(const float4*)&wb[0];
      *(float4*)&wreg[4]  = *(const float4*)&wb[4];
      *(float4*)&wreg[8]  = *(const float4*)&wb[8];
      *(float4*)&wreg[12] = *(const float4*)&wb[12];
      *(float4*)&wreg[16] = *(const float4*)&wb[16];
      *(float4*)&wreg[20] = *(const float4*)&wb[20];
      *(float4*)&wreg[24] = *(const float4*)&wb[24];

      const int cc = cc0 + ccl;
      const float* pb = &pooled[cc * 144];
      float rows[2][12];
      *(float4*)&rows[0][0] = *(const float4*)&pb[r0 * 12];
      *(float4*)&rows[0][4] = *(const float4*)&pb[r0 * 12 + 4];
      *(float4*)&rows[0][8] = *(const float4*)&pb[r0 * 12 + 8];
      #pragma unroll
      for (int ky = 0; ky < 5; ky++) {
        float* B = rows[(ky + 1) & 1];
        const float* bp = &pb[(r0 + ky + 1) * 12];
        *(float4*)&B[0] = *(const float4*)&bp[0];
        *(float4*)&B[4] = *(const float4*)&bp[4];
        *(float4*)&B[8] = *(const float4*)&bp[8];
        const float* A = rows[ky & 1];
        #pragma unroll
        for (int kx = 0; kx < 5; kx++) {
          const float w = wreg[ky * 5 + kx];
          #pragma unroll
          for (int ox = 0; ox < 8; ox++) acc0[ox] = fmaf(A[ox + kx], w, acc0[ox]);
          #pragma unroll
          for (int ox = 0; ox < 8; ox++) acc1[ox] = fmaf(B[ox + kx], w, acc1[ox]);
        }
      }
    }
  }

  float asum = 0.0f;
  #pragma unroll
  for (int i = 0; i < 8; i++) asum += fabsf(acc0[i]) + fabsf(acc1[i]);
  float tot = blockReduceSumF(asum, red, tid, 4);
  float delta = (0.7f * tot) / 4096.0f;

  float msum = 0.0f, mcnt = 0.0f;
  #pragma unroll
  for (int i = 0; i < 8; i++) {
    float f0 = fabsf(acc0[i]);
    if (f0 > delta) { msum += f0; mcnt += 1.0f; }
    float f1 = fabsf(acc1[i]);
    if (f1 > delta) { msum += f1; mcnt += 1.0f; }
  }
  msum = blockReduceSumF(msum, red, tid, 4);
  mcnt = blockReduceSumF(mcnt, red, tid, 4);
  if (tid == 0) alpha2[smp] = (mcnt > 0.0f) ? (msum / mcnt) : 0.0f;

  signed char* so = s2full + (size_t)smp * 4096 + c2 * 64 + r0 * 8;
  #pragma unroll
  for (int ox = 0; ox < 8; ox++) {
    float v = acc0[ox];
    so[ox] = (signed char)((v > delta) ? 1 : ((v < -delta) ? -1 : 0));
  }
  #pragma unroll
  for (int ox = 0; ox < 8; ox++) {
    float v = acc1[ox];
    so[8 + ox] = (signed char)((v > delta) ? 1 : ((v < -delta) ? -1 : 0));
  }
}

// ---------------- K3: 4 samples/block — R11 verbatim ----
__global__ __launch_bounds__(1024, 4) void k3_fc(
    const signed char* __restrict__ s2full, const float* __restrict__ alpha2,
    const float* __restrict__ w1f, const float* __restrict__ f1b,
    const float* __restrict__ w2f, const float* __restrict__ f2b,
    const float* __restrict__ g2, const float* __restrict__ bt2,
    float* __restrict__ out) {
  __shared__ float h[4][1024];
  __shared__ float fco[4][512];
  __shared__ float h3[4][512];
  __shared__ float g2l[64], bt2l[64];
  __shared__ float redm[4][4];
  __shared__ float out2[4][10];

  const int tid = threadIdx.x;
  const int blk = blockIdx.x;
  const float BNINV = (float)(1.0 / sqrt(1.0 + 1e-5));

  if (tid < 64) { g2l[tid] = g2[tid] * BNINV; bt2l[tid] = bt2[tid]; }
  __syncthreads();

  for (int e = tid; e < 4096; e += 1024) {
    int s = e >> 10;
    int j = e & 1023;
    int cc = j >> 4;
    int r = j & 15;
    int py = r >> 2;
    int px = r & 3;
    const signed char* sp = s2full + (size_t)(blk * 4 + s) * 4096 + cc * 64 + (py * 2) * 8 + px * 2;
    float a2 = alpha2[blk * 4 + s];
    float m = -1e30f;
    #pragma unroll
    for (int dy = 0; dy < 2; dy++)
      #pragma unroll
      for (int dx = 0; dx < 2; dx++) {
        float v = ((float)sp[dy * 8 + dx] * a2) * g2l[cc] + bt2l[cc];
        m = (v > m) ? v : m;
      }
    h[s][j] = (m > 0.0f) ? m : 0.0f;
  }
  __syncthreads();

  const int lane = tid & 63;
  const int wid = tid >> 6;
  float hreg[4][16];
  #pragma unroll
  for (int s = 0; s < 4; s++)
    #pragma unroll
    for (int m = 0; m < 4; m++)
      *(float4*)&hreg[s][m * 4] = *(const float4*)&h[s][m * 256 + (lane << 2)];

  for (int k = 0; k < 32; k++) {
    const int o = (wid << 5) + k;
    const float* wp = w1f + o * 1024 + (lane << 2);
    float wl[16];
    *(float4*)&wl[0]  = *(const float4*)&wp[0];
    *(float4*)&wl[4]  = *(const float4*)&wp[256];
    *(float4*)&wl[8]  = *(const float4*)&wp[512];
    *(float4*)&wl[12] = *(const float4*)&wp[768];
    float ac0 = 0.0f, ac1 = 0.0f, ac2 = 0.0f, ac3 = 0.0f;
    #pragma unroll
    for (int m = 0; m < 16; m++) {
      const float w = wl[m];
      ac0 = fmaf(hreg[0][m], w, ac0);
      ac1 = fmaf(hreg[1][m], w, ac1);
      ac2 = fmaf(hreg[2][m], w, ac2);
      ac3 = fmaf(hreg[3][m], w, ac3);
    }
    #pragma unroll
    for (int off = 32; off > 0; off >>= 1) {
      ac0 += __shfl_xor(ac0, off);
      ac1 += __shfl_xor(ac1, off);
      ac2 += __shfl_xor(ac2, off);
      ac3 += __shfl_xor(ac3, off);
    }
    if (lane == 0) {
      const float b = f1b[o];
      fco[0][o] = ac0 + b;
      fco[1][o] = ac1 + b;
      fco[2][o] = ac2 + b;
      fco[3][o] = ac3 + b;
    }
  }
  __syncthreads();

  const int sg = tid >> 8;
  const int tj = tid & 255;
  float v0 = fco[sg][tj];
  float v1 = fco[sg][tj + 256];
  float av0 = fabsf(v0), av1 = fabsf(v1);
  float tot = groupReduce4w(av0 + av1, redm[sg], tj);
  float delta = (0.7f * tot) / 512.0f;
  float m0 = (av0 > delta) ? av0 : 0.0f;
  float m1 = (av1 > delta) ? av1 : 0.0f;
  float msum = groupReduce4w(m0 + m1, redm[sg], tj);
  float mcnt = groupReduce4w(((av0 > delta) ? 1.0f : 0.0f) + ((av1 > delta) ? 1.0f : 0.0f),
                             redm[sg], tj);
  float alpha3 = (mcnt > 0.0f) ? (msum / mcnt) : 0.0f;
  {
    float t0 = (v0 > delta) ? 1.0f : ((v0 < -delta) ? -1.0f : 0.0f);
    float hv0 = t0 * alpha3;
    h3[sg][tj] = (hv0 > 0.0f) ? hv0 : 0.0f;
    float t1 = (v1 > delta) ? 1.0f : ((v1 < -delta) ? -1.0f : 0.0f);
    float hv1 = t1 * alpha3;
    h3[sg][tj + 256] = (hv1 > 0.0f) ? hv1 : 0.0f;
  }
  __syncthreads();

  for (int t = wid; t < 40; t += 16) {
    int s = t / 10;
    int o = t - s * 10;
    float acc = 0.0f;
    #pragma unroll
    for (int m = 0; m < 8; m++) {
      int j = lane + (m << 6);
      acc = fmaf(h3[s][j], w2f[o * 512 + j], acc);
    }
    #pragma unroll
    for (int off = 32; off > 0; off >>= 1) acc += __shfl_xor(acc, off);
    if (lane == 0) out2[s][o] = acc + f2b[o];
  }
  __syncthreads();

  if (tid < 4) {
    int s = tid;
    float t2 = 0.0f;
    for (int i = 0; i < 10; i++) t2 += fabsf(out2[s][i]);
    float d = (0.7f * t2) / 10.0f;
    float ms = 0.0f, mc = 0.0f;
    for (int i = 0; i < 10; i++) {
      float a = fabsf(out2[s][i]);
      if (a > d) { ms += a; mc += 1.0f; }
    }
    float al = (mc > 0.0f) ? (ms / mc) : 0.0f;
    for (int i = 0; i < 10; i++) {
      float vv = out2[s][i];
      float sv = (vv > d) ? 1.0f : ((vv < -d) ? -1.0f : 0.0f);
      out[(size_t)(blk * 4 + s) * 10 + i] = sv * al;
    }
  }
}

// assumption-violation marker: fills out with a readable constant
__global__ void k_marker(float* __restrict__ out, int n, float val) {
  int i = blockIdx.x * 256 + threadIdx.x;
  if (i < n) out[i] = val;
}

extern "C" void kernel_launch(void* const* d_in, const int* in_sizes, int n_in,
                              void* d_out, int out_size, void* d_ws, size_t ws_size,
                              hipStream_t stream) {
  float* out = (float*)d_out;

  static const int expect[13] = {1605632, 800, 32, 32, 32, 51200, 64, 64, 64,
                                 524288, 512, 5120, 10};
  float marker = 0.0f;
  if (n_in != 13) marker = 304.0f;
  else {
    for (int i = 0; i < 13; i++)
      if (in_sizes[i] != expect[i]) { marker = 320.0f + 16.0f * i; break; }
  }
  if (marker == 0.0f && out_size != 20480) marker = 560.0f;

  float* alpha1 = (float*)d_ws;                           // 2048
  float* alpha2 = alpha1 + BATCH;                         // 2048
  signed char* s1full = (signed char*)(alpha2 + BATCH);   // 2048*18432
  signed char* s2full = s1full + (size_t)BATCH * 18432;   // 2048*4096
  size_t needed = (size_t)((s2full + (size_t)BATCH * 4096) - (signed char*)d_ws);
  if (marker == 0.0f && ws_size < needed) marker = 576.0f;

  if (marker != 0.0f) {
    k_marker<<<dim3((out_size + 255) / 256), dim3(256), 0, stream>>>(out, out_size, marker);
    return;
  }

  const float* x   = (const float*)d_in[0];
  const float* c1w = (const float*)d_in[1];
  const float* c1b = (const float*)d_in[2];
  const float* g1  = (const float*)d_in[3];
  const float* bt1 = (const float*)d_in[4];
  const float* c2w = (const float*)d_in[5];
  const float* c2b = (const float*)d_in[6];
  const float* g2  = (const float*)d_in[7];
  const float* bt2 = (const float*)d_in[8];
  const float* f1w = (const float*)d_in[9];
  const float* f1b = (const float*)d_in[10];
  const float* f2w = (const float*)d_in[11];
  const float* f2b = (const float*)d_in[12];

  k1_conv1<<<dim3(BATCH), dim3(512), 0, stream>>>(x, c1w, c1b, s1full, alpha1);
  k2_conv2<<<dim3(BATCH), dim3(256), 0, stream>>>(s1full, alpha1, c2w, c2b, g1, bt1, s2full, alpha2);
  k3_fc<<<dim3(BATCH / 4), dim3(1024), 0, stream>>>(s2full, alpha2, f1w, f1b, f2w, f2b, g2, bt2, out);
}

// Round 13
// 385.923 us; speedup vs baseline: 1.3099x; 1.3099x over previous
//
#include <hip/hip_runtime.h>

#define BATCH 2048

// block-wide f32 sum; all threads get the result. red >= 32 floats.
__device__ __forceinline__ float blockReduceSumF(float v, float* red, int tid, int nwaves) {
  #pragma unroll
  for (int off = 32; off > 0; off >>= 1) v += __shfl_xor(v, off);
  __syncthreads();
  if ((tid & 63) == 0) red[tid >> 6] = v;
  __syncthreads();
  if (tid == 0) {
    float s = red[0];
    for (int i = 1; i < nwaves; i++) s += red[i];
    red[31] = s;
  }
  __syncthreads();
  return red[31];
}

// 4-wave (256-thread) group reduce; seg = 4-float LDS segment for this group.
__device__ __forceinline__ float groupReduce4w(float v, float* seg, int tj) {
  #pragma unroll
  for (int off = 32; off > 0; off >>= 1) v += __shfl_xor(v, off);
  __syncthreads();
  if ((tj & 63) == 0) seg[tj >> 6] = v;
  __syncthreads();
  return (seg[0] + seg[1]) + (seg[2] + seg[3]);
}

// ---------------- K1: conv1 + ternarize -> sign map + alpha1 (f32) — R11 verbatim ----
__global__ __launch_bounds__(512, 6) void k1_conv1(
    const float* __restrict__ x, const float* __restrict__ w1, const float* __restrict__ b1,
    signed char* __restrict__ s1full, float* __restrict__ alpha1) {
  __shared__ float xs[784];
  __shared__ float wsm[800];
  __shared__ float red[32];

  const int tid = threadIdx.x;
  const int smp = blockIdx.x;

  for (int j = tid; j < 784; j += 512) xs[j] = x[smp * 784 + j];
  for (int j = tid; j < 800; j += 512) wsm[j] = w1[j];
  __syncthreads();

  const int c = tid >> 4;
  const int g = tid & 15;
  const float bias = b1[c];
  const float* wc = &wsm[c * 25];

  float a[36];
  float asum = 0.0f;
  #pragma unroll
  for (int tt = 0; tt < 3; tt++) {
    const int t = g + (tt << 4);
    const int r = t >> 1;
    const int hx = (t & 1) * 12;
    float acc[12];
    #pragma unroll
    for (int i = 0; i < 12; i++) acc[i] = bias;
    #pragma unroll
    for (int ky = 0; ky < 5; ky++) {
      const float* xp = &xs[(r + ky) * 28 + hx];
      float xrow[16];
      *(float4*)&xrow[0]  = *(const float4*)&xp[0];
      *(float4*)&xrow[4]  = *(const float4*)&xp[4];
      *(float4*)&xrow[8]  = *(const float4*)&xp[8];
      *(float4*)&xrow[12] = *(const float4*)&xp[12];
      #pragma unroll
      for (int kx = 0; kx < 5; kx++) {
        const float w = wc[ky * 5 + kx];
        #pragma unroll
        for (int i = 0; i < 12; i++) acc[i] = fmaf(xrow[i + kx], w, acc[i]);
      }
    }
    #pragma unroll
    for (int i = 0; i < 12; i++) { a[tt * 12 + i] = acc[i]; asum += fabsf(acc[i]); }
  }

  float tot = blockReduceSumF(asum, red, tid, 8);
  float delta = (0.7f * tot) / 18432.0f;

  float msum = 0.0f, mcnt = 0.0f;
  #pragma unroll
  for (int i = 0; i < 36; i++) {
    float fa = fabsf(a[i]);
    if (fa > delta) { msum += fa; mcnt += 1.0f; }
  }
  msum = blockReduceSumF(msum, red, tid, 8);
  mcnt = blockReduceSumF(mcnt, red, tid, 8);
  if (tid == 0) alpha1[smp] = (mcnt > 0.0f) ? (msum / mcnt) : 0.0f;

  signed char* sp = s1full + (size_t)smp * 18432 + c * 576 + g * 12;
  #pragma unroll
  for (int tt = 0; tt < 3; tt++) {
    #pragma unroll
    for (int i = 0; i < 12; i++) {
      float v = a[tt * 12 + i];
      int sv = (v > delta) ? 1 : ((v < -delta) ? -1 : 0);
      sp[tt * 192 + i] = (signed char)sv;
    }
  }
}

// ---------------- K2: BN1+maxpool+relu, conv2, ternarize — R11 verbatim (198 µs) ----
__global__ __launch_bounds__(256, 6) void k2_conv2(
    const signed char* __restrict__ s1full, const float* __restrict__ alpha1,
    const float* __restrict__ w2, const float* __restrict__ b2,
    const float* __restrict__ g1, const float* __restrict__ bt1,
    signed char* __restrict__ s2full, float* __restrict__ alpha2) {
  __shared__ float pooled[4608];
  __shared__ float g1l[32], bt1l[32];
  __shared__ float red[32];

  const int tid = threadIdx.x;
  const int smp = blockIdx.x;
  const float BNINV = (float)(1.0 / sqrt(1.0 + 1e-5));

  if (tid < 32) { g1l[tid] = g1[tid] * BNINV; bt1l[tid] = bt1[tid]; }
  __syncthreads();

  const float a1 = alpha1[smp];
  for (int j = tid; j < 4608; j += 256) {
    int cc = j / 144;
    int r = j - cc * 144;
    int py = r / 12;
    int px = r - py * 12;
    const signed char* sp = s1full + (size_t)smp * 18432 + cc * 576 + (py * 2) * 24 + px * 2;
    float m = -1e30f;
    #pragma unroll
    for (int dy = 0; dy < 2; dy++)
      #pragma unroll
      for (int dx = 0; dx < 2; dx++) {
        float v = ((float)sp[dy * 24 + dx] * a1) * g1l[cc] + bt1l[cc];
        m = (v > m) ? v : m;
      }
    pooled[j] = (m > 0.0f) ? m : 0.0f;
  }
  __syncthreads();

  const int c2 = tid >> 2;
  const int q = tid & 3;
  const int r0 = q << 1;
  const float bias = b2[c2];
  float acc0[8], acc1[8];
  #pragma unroll
  for (int i = 0; i < 8; i++) { acc0[i] = bias; acc1[i] = bias; }

  for (int cc = 0; cc < 32; cc++) {
    const float* wb = w2 + (c2 * 32 + cc) * 25;
    const float* pb = &pooled[cc * 144];
    float rows[2][12];
    *(float4*)&rows[0][0] = *(const float4*)&pb[r0 * 12];
    *(float4*)&rows[0][4] = *(const float4*)&pb[r0 * 12 + 4];
    *(float4*)&rows[0][8] = *(const float4*)&pb[r0 * 12 + 8];
    #pragma unroll
    for (int ky = 0; ky < 5; ky++) {
      float* B = rows[(ky + 1) & 1];
      const float* bp = &pb[(r0 + ky + 1) * 12];
      *(float4*)&B[0] = *(const float4*)&bp[0];
      *(float4*)&B[4] = *(const float4*)&bp[4];
      *(float4*)&B[8] = *(const float4*)&bp[8];
      const float* A = rows[ky & 1];
      #pragma unroll
      for (int kx = 0; kx < 5; kx++) {
        const float w = wb[ky * 5 + kx];
        #pragma unroll
        for (int ox = 0; ox < 8; ox++) acc0[ox] = fmaf(A[ox + kx], w, acc0[ox]);
        #pragma unroll
        for (int ox = 0; ox < 8; ox++) acc1[ox] = fmaf(B[ox + kx], w, acc1[ox]);
      }
    }
  }

  float asum = 0.0f;
  #pragma unroll
  for (int i = 0; i < 8; i++) asum += fabsf(acc0[i]) + fabsf(acc1[i]);
  float tot = blockReduceSumF(asum, red, tid, 4);
  float delta = (0.7f * tot) / 4096.0f;

  float msum = 0.0f, mcnt = 0.0f;
  #pragma unroll
  for (int i = 0; i < 8; i++) {
    float f0 = fabsf(acc0[i]);
    if (f0 > delta) { msum += f0; mcnt += 1.0f; }
    float f1 = fabsf(acc1[i]);
    if (f1 > delta) { msum += f1; mcnt += 1.0f; }
  }
  msum = blockReduceSumF(msum, red, tid, 4);
  mcnt = blockReduceSumF(mcnt, red, tid, 4);
  if (tid == 0) alpha2[smp] = (mcnt > 0.0f) ? (msum / mcnt) : 0.0f;

  signed char* so = s2full + (size_t)smp * 4096 + c2 * 64 + r0 * 8;
  #pragma unroll
  for (int ox = 0; ox < 8; ox++) {
    float v = acc0[ox];
    so[ox] = (signed char)((v > delta) ? 1 : ((v < -delta) ? -1 : 0));
  }
  #pragma unroll
  for (int ox = 0; ox < 8; ox++) {
    float v = acc1[ox];
    so[8 + ox] = (signed char)((v > delta) ? 1 : ((v < -delta) ? -1 : 0));
  }
}

// ---------------- K0t: transpose fc1 weights into w1t[k][o] (runs after k2,
// into the then-dead s1full region). writes coalesced; reads L2-resident. ----
__global__ void k0_transpose(const float* __restrict__ w1f, float* __restrict__ w1t) {
  int i = blockIdx.x * 256 + threadIdx.x;  // i over 524288
  int k = i >> 9;
  int o = i & 511;
  w1t[i] = w1f[o * 1024 + k];
}

// ---------------- K3: 4 samples/block; fc1 via transposed weights:
// thread = (kp = tid>>7, og = tid&127) owns outputs 4og..4og+3, k-range 128;
// per k: 1 coalesced float4 w-load + 1 broadcast b128 h-load + 16 FMA. No shuffles.
// Partials reduced via LDS (kp ascending — deterministic). ----
__global__ __launch_bounds__(1024, 4) void k3_fc(
    const signed char* __restrict__ s2full, const float* __restrict__ alpha2,
    const float* __restrict__ w1t, const float* __restrict__ f1b,
    const float* __restrict__ w2f, const float* __restrict__ f2b,
    const float* __restrict__ g2, const float* __restrict__ bt2,
    float* __restrict__ out) {
  __shared__ float S[16384];          // phase1-2: h4[k][s] (first 4096); then pbuf; then h3
  __shared__ float fco[4][512];
  __shared__ float g2l[64], bt2l[64];
  __shared__ float redm[4][4];
  __shared__ float out2[4][10];

  const int tid = threadIdx.x;
  const int blk = blockIdx.x;  // samples blk*4 .. blk*4+3
  const float BNINV = (float)(1.0 / sqrt(1.0 + 1e-5));

  if (tid < 64) { g2l[tid] = g2[tid] * BNINV; bt2l[tid] = bt2[tid]; }
  __syncthreads();

  // phase 1: h4[j][s] (literal BN+maxpool+relu), j = flatten index, s = sample
  float* h4 = S;
  for (int e = tid; e < 4096; e += 1024) {
    int j = e >> 2;
    int s = e & 3;
    int cc = j >> 4;
    int r = j & 15;
    int py = r >> 2;
    int px = r & 3;
    const signed char* sp = s2full + (size_t)(blk * 4 + s) * 4096 + cc * 64 + (py * 2) * 8 + px * 2;
    float a2 = alpha2[blk * 4 + s];
    float m = -1e30f;
    #pragma unroll
    for (int dy = 0; dy < 2; dy++)
      #pragma unroll
      for (int dx = 0; dx < 2; dx++) {
        float v = ((float)sp[dy * 8 + dx] * a2) * g2l[cc] + bt2l[cc];
        m = (v > m) ? v : m;
      }
    h4[j * 4 + s] = (m > 0.0f) ? m : 0.0f;
  }
  __syncthreads();

  // phase 2: fc1 partials
  const int kp = tid >> 7;   // 0..7
  const int og = tid & 127;  // output quad
  float a00=0,a01=0,a02=0,a03=0, a10=0,a11=0,a12=0,a13=0;
  float a20=0,a21=0,a22=0,a23=0, a30=0,a31=0,a32=0,a33=0;
  const float4* w4 = (const float4*)w1t;
  const float4* h44 = (const float4*)h4;
  const int kbase = kp << 7;
  for (int kk = 0; kk < 128; kk++) {
    const int k = kbase + kk;
    const float4 wv = w4[(k << 7) + og];   // w1t[k][4og..4og+3]
    const float4 hv = h44[k];              // h[k][0..3] — wave-uniform broadcast
    a00 = fmaf(hv.x, wv.x, a00); a01 = fmaf(hv.y, wv.x, a01);
    a02 = fmaf(hv.z, wv.x, a02); a03 = fmaf(hv.w, wv.x, a03);
    a10 = fmaf(hv.x, wv.y, a10); a11 = fmaf(hv.y, wv.y, a11);
    a12 = fmaf(hv.z, wv.y, a12); a13 = fmaf(hv.w, wv.y, a13);
    a20 = fmaf(hv.x, wv.z, a20); a21 = fmaf(hv.y, wv.z, a21);
    a22 = fmaf(hv.z, wv.z, a22); a23 = fmaf(hv.w, wv.z, a23);
    a30 = fmaf(hv.x, wv.w, a30); a31 = fmaf(hv.y, wv.w, a31);
    a32 = fmaf(hv.z, wv.w, a32); a33 = fmaf(hv.w, wv.w, a33);
  }
  __syncthreads();  // h4 dead — S becomes pbuf[kp][og][i][s]
  {
    float4* p4 = (float4*)S;
    const int base = (kp << 9) + (og << 2);
    p4[base + 0] = make_float4(a00, a01, a02, a03);
    p4[base + 1] = make_float4(a10, a11, a12, a13);
    p4[base + 2] = make_float4(a20, a21, a22, a23);
    p4[base + 3] = make_float4(a30, a31, a32, a33);
  }
  __syncthreads();

  // reduce partials (kp ascending) -> fco[s][o]
  for (int p = tid; p < 2048; p += 1024) {
    int o = p >> 2;
    int s = p & 3;
    float v = S[p];
    #pragma unroll
    for (int kp2 = 1; kp2 < 8; kp2++) v += S[kp2 * 2048 + p];
    fco[s][o] = v + f1b[o];
  }
  __syncthreads();

  // phase 3: per-sample ternarize+relu of fc1 (4-wave groups)
  float (*h3)[512] = (float(*)[512])S;  // pbuf dead
  const int sg = tid >> 8;
  const int tj = tid & 255;
  float v0 = fco[sg][tj];
  float v1 = fco[sg][tj + 256];
  float av0 = fabsf(v0), av1 = fabsf(v1);
  float tot = groupReduce4w(av0 + av1, redm[sg], tj);
  float delta = (0.7f * tot) / 512.0f;
  float m0 = (av0 > delta) ? av0 : 0.0f;
  float m1 = (av1 > delta) ? av1 : 0.0f;
  float msum = groupReduce4w(m0 + m1, redm[sg], tj);
  float mcnt = groupReduce4w(((av0 > delta) ? 1.0f : 0.0f) + ((av1 > delta) ? 1.0f : 0.0f),
                             redm[sg], tj);
  float alpha3 = (mcnt > 0.0f) ? (msum / mcnt) : 0.0f;
  {
    float t0 = (v0 > delta) ? 1.0f : ((v0 < -delta) ? -1.0f : 0.0f);
    float hv0 = t0 * alpha3;
    h3[sg][tj] = (hv0 > 0.0f) ? hv0 : 0.0f;
    float t1 = (v1 > delta) ? 1.0f : ((v1 < -delta) ? -1.0f : 0.0f);
    float hv1 = t1 * alpha3;
    h3[sg][tj + 256] = (hv1 > 0.0f) ? hv1 : 0.0f;
  }
  __syncthreads();

  // phase 4: fc2 — 40 (sample, output) tasks over 16 waves
  const int lane = tid & 63;
  const int wid = tid >> 6;
  for (int t = wid; t < 40; t += 16) {
    int s = t / 10;
    int o = t - s * 10;
    float acc = 0.0f;
    #pragma unroll
    for (int m = 0; m < 8; m++) {
      int j = lane + (m << 6);
      acc = fmaf(h3[s][j], w2f[o * 512 + j], acc);
    }
    #pragma unroll
    for (int off = 32; off > 0; off >>= 1) acc += __shfl_xor(acc, off);
    if (lane == 0) out2[s][o] = acc + f2b[o];
  }
  __syncthreads();

  // phase 5: final ternarize per sample -> float out
  if (tid < 4) {
    int s = tid;
    float t2 = 0.0f;
    for (int i = 0; i < 10; i++) t2 += fabsf(out2[s][i]);
    float d = (0.7f * t2) / 10.0f;
    float ms = 0.0f, mc = 0.0f;
    for (int i = 0; i < 10; i++) {
      float a = fabsf(out2[s][i]);
      if (a > d) { ms += a; mc += 1.0f; }
    }
    float al = (mc > 0.0f) ? (ms / mc) : 0.0f;
    for (int i = 0; i < 10; i++) {
      float vv = out2[s][i];
      float sv = (vv > d) ? 1.0f : ((vv < -d) ? -1.0f : 0.0f);
      out[(size_t)(blk * 4 + s) * 10 + i] = sv * al;
    }
  }
}

// assumption-violation marker
__global__ void k_marker(float* __restrict__ out, int n, float val) {
  int i = blockIdx.x * 256 + threadIdx.x;
  if (i < n) out[i] = val;
}

extern "C" void kernel_launch(void* const* d_in, const int* in_sizes, int n_in,
                              void* d_out, int out_size, void* d_ws, size_t ws_size,
                              hipStream_t stream) {
  float* out = (float*)d_out;

  static const int expect[13] = {1605632, 800, 32, 32, 32, 51200, 64, 64, 64,
                                 524288, 512, 5120, 10};
  float marker = 0.0f;
  if (n_in != 13) marker = 304.0f;
  else {
    for (int i = 0; i < 13; i++)
      if (in_sizes[i] != expect[i]) { marker = 320.0f + 16.0f * i; break; }
  }
  if (marker == 0.0f && out_size != 20480) marker = 560.0f;

  float* alpha1 = (float*)d_ws;                           // 2048
  float* alpha2 = alpha1 + BATCH;                         // 2048
  signed char* s1full = (signed char*)(alpha2 + BATCH);   // 2048*18432 (dead after k2;
                                                          //  first 2MB reused as w1t)
  signed char* s2full = s1full + (size_t)BATCH * 18432;   // 2048*4096
  size_t needed = (size_t)((s2full + (size_t)BATCH * 4096) - (signed char*)d_ws);
  if (marker == 0.0f && ws_size < needed) marker = 576.0f;

  if (marker != 0.0f) {
    k_marker<<<dim3((out_size + 255) / 256), dim3(256), 0, stream>>>(out, out_size, marker);
    return;
  }

  const float* x   = (const float*)d_in[0];
  const float* c1w = (const float*)d_in[1];
  const float* c1b = (const float*)d_in[2];
  const float* g1  = (const float*)d_in[3];
  const float* bt1 = (const float*)d_in[4];
  const float* c2w = (const float*)d_in[5];
  const float* c2b = (const float*)d_in[6];
  const float* g2  = (const float*)d_in[7];
  const float* bt2 = (const float*)d_in[8];
  const float* f1w = (const float*)d_in[9];
  const float* f1b = (const float*)d_in[10];
  const float* f2w = (const float*)d_in[11];
  const float* f2b = (const float*)d_in[12];

  float* w1t = (float*)s1full;  // 524288 floats, 16KB-aligned offset

  k1_conv1<<<dim3(BATCH), dim3(512), 0, stream>>>(x, c1w, c1b, s1full, alpha1);
  k2_conv2<<<dim3(BATCH), dim3(256), 0, stream>>>(s1full, alpha1, c2w, c2b, g1, bt1, s2full, alpha2);
  k0_transpose<<<dim3(2048), dim3(256), 0, stream>>>(f1w, w1t);
  k3_fc<<<dim3(BATCH / 4), dim3(1024), 0, stream>>>(s2full, alpha2, w1t, f1b, f2w, f2b, g2, bt2, out);
}

// Round 14
// 375.288 us; speedup vs baseline: 1.3471x; 1.0283x over previous
//
#include <hip/hip_runtime.h>

#define BATCH 2048

// block-wide f32 sum; all threads get the result. red >= 32 floats.
__device__ __forceinline__ float blockReduceSumF(float v, float* red, int tid, int nwaves) {
  #pragma unroll
  for (int off = 32; off > 0; off >>= 1) v += __shfl_xor(v, off);
  __syncthreads();
  if ((tid & 63) == 0) red[tid >> 6] = v;
  __syncthreads();
  if (tid == 0) {
    float s = red[0];
    for (int i = 1; i < nwaves; i++) s += red[i];
    red[31] = s;
  }
  __syncthreads();
  return red[31];
}

// packed 2-value block reduce (one barrier sequence); per-component order identical
// to two sequential blockReduceSumF calls -> bit-exact. red >= 32 floats; nwaves <= 8.
__device__ __forceinline__ float2 blockReduceSum2F(float a, float b, float* red, int tid, int nwaves) {
  #pragma unroll
  for (int off = 32; off > 0; off >>= 1) { a += __shfl_xor(a, off); b += __shfl_xor(b, off); }
  __syncthreads();
  if ((tid & 63) == 0) { red[tid >> 6] = a; red[(tid >> 6) + 16] = b; }
  __syncthreads();
  if (tid == 0) {
    float sa = red[0], sb = red[16];
    for (int i = 1; i < nwaves; i++) { sa += red[i]; sb += red[16 + i]; }
    red[30] = sa; red[31] = sb;
  }
  __syncthreads();
  return make_float2(red[30], red[31]);
}

// 4-wave (256-thread) group reduce; seg = 4-float LDS segment for this group.
__device__ __forceinline__ float groupReduce4w(float v, float* seg, int tj) {
  #pragma unroll
  for (int off = 32; off > 0; off >>= 1) v += __shfl_xor(v, off);
  __syncthreads();
  if ((tj & 63) == 0) seg[tj >> 6] = v;
  __syncthreads();
  return (seg[0] + seg[1]) + (seg[2] + seg[3]);
}

// ---------------- K0a: transpose conv2 weights -> w2t[cc][k][c2] (200 KB) ----------------
__global__ void k0_w2t(const float* __restrict__ w2, float* __restrict__ w2t) {
  int i = blockIdx.x * 256 + threadIdx.x;  // over 51200
  if (i >= 51200) return;
  int c2 = i / 800;
  int r = i - c2 * 800;           // cc*25 + k
  w2t[r * 64 + c2] = w2[i];
}

// ---------------- K1: conv1 + ternarize -> sign map + alpha1 (f32) ----------------
__global__ __launch_bounds__(512, 6) void k1_conv1(
    const float* __restrict__ x, const float* __restrict__ w1, const float* __restrict__ b1,
    signed char* __restrict__ s1full, float* __restrict__ alpha1) {
  __shared__ float xs[784];
  __shared__ float wsm[800];
  __shared__ float red[32];

  const int tid = threadIdx.x;
  const int smp = blockIdx.x;

  for (int j = tid; j < 784; j += 512) xs[j] = x[smp * 784 + j];
  for (int j = tid; j < 800; j += 512) wsm[j] = w1[j];
  __syncthreads();

  const int c = tid >> 4;
  const int g = tid & 15;
  const float bias = b1[c];
  const float* wc = &wsm[c * 25];

  float a[36];
  float asum = 0.0f;
  #pragma unroll
  for (int tt = 0; tt < 3; tt++) {
    const int t = g + (tt << 4);
    const int r = t >> 1;
    const int hx = (t & 1) * 12;
    float acc[12];
    #pragma unroll
    for (int i = 0; i < 12; i++) acc[i] = bias;
    #pragma unroll
    for (int ky = 0; ky < 5; ky++) {
      const float* xp = &xs[(r + ky) * 28 + hx];
      float xrow[16];
      *(float4*)&xrow[0]  = *(const float4*)&xp[0];
      *(float4*)&xrow[4]  = *(const float4*)&xp[4];
      *(float4*)&xrow[8]  = *(const float4*)&xp[8];
      *(float4*)&xrow[12] = *(const float4*)&xp[12];
      #pragma unroll
      for (int kx = 0; kx < 5; kx++) {
        const float w = wc[ky * 5 + kx];
        #pragma unroll
        for (int i = 0; i < 12; i++) acc[i] = fmaf(xrow[i + kx], w, acc[i]);
      }
    }
    #pragma unroll
    for (int i = 0; i < 12; i++) { a[tt * 12 + i] = acc[i]; asum += fabsf(acc[i]); }
  }

  float tot = blockReduceSumF(asum, red, tid, 8);
  float delta = (0.7f * tot) / 18432.0f;

  float msum = 0.0f, mcnt = 0.0f;
  #pragma unroll
  for (int i = 0; i < 36; i++) {
    float fa = fabsf(a[i]);
    if (fa > delta) { msum += fa; mcnt += 1.0f; }
  }
  float2 mm = blockReduceSum2F(msum, mcnt, red, tid, 8);
  if (tid == 0) alpha1[smp] = (mm.y > 0.0f) ? (mm.x / mm.y) : 0.0f;

  signed char* sp = s1full + (size_t)smp * 18432 + c * 576 + g * 12;
  #pragma unroll
  for (int tt = 0; tt < 3; tt++) {
    #pragma unroll
    for (int i = 0; i < 12; i++) {
      float v = a[tt * 12 + i];
      int sv = (v > delta) ? 1 : ((v < -delta) ? -1 : 0);
      sp[tt * 192 + i] = (signed char)sv;
    }
  }
}

// ---------------- K2: BN1+maxpool+relu, conv2, ternarize ----
// R14: weights read from transposed w2t[cc][k][c2] — per (cc,k) a wave touches 16
// consecutive dwords (x4-lane broadcast) = 1-2 cache lines, L1-resident, instead of a
// 16-line gather. FMA order/operands bitwise-identical to R13.
__global__ __launch_bounds__(256, 6) void k2_conv2(
    const signed char* __restrict__ s1full, const float* __restrict__ alpha1,
    const float* __restrict__ w2t, const float* __restrict__ b2,
    const float* __restrict__ g1, const float* __restrict__ bt1,
    signed char* __restrict__ s2full, float* __restrict__ alpha2) {
  __shared__ float pooled[4608];
  __shared__ float g1l[32], bt1l[32];
  __shared__ float red[32];

  const int tid = threadIdx.x;
  const int smp = blockIdx.x;
  const float BNINV = (float)(1.0 / sqrt(1.0 + 1e-5));

  if (tid < 32) { g1l[tid] = g1[tid] * BNINV; bt1l[tid] = bt1[tid]; }
  __syncthreads();

  const float a1 = alpha1[smp];
  for (int j = tid; j < 4608; j += 256) {
    int cc = j / 144;
    int r = j - cc * 144;
    int py = r / 12;
    int px = r - py * 12;
    const signed char* sp = s1full + (size_t)smp * 18432 + cc * 576 + (py * 2) * 24 + px * 2;
    float m = -1e30f;
    #pragma unroll
    for (int dy = 0; dy < 2; dy++)
      #pragma unroll
      for (int dx = 0; dx < 2; dx++) {
        float v = ((float)sp[dy * 24 + dx] * a1) * g1l[cc] + bt1l[cc];
        m = (v > m) ? v : m;
      }
    pooled[j] = (m > 0.0f) ? m : 0.0f;
  }
  __syncthreads();

  const int c2 = tid >> 2;
  const int q = tid & 3;
  const int r0 = q << 1;
  const float bias = b2[c2];
  float acc0[8], acc1[8];
  #pragma unroll
  for (int i = 0; i < 8; i++) { acc0[i] = bias; acc1[i] = bias; }

  for (int cc = 0; cc < 32; cc++) {
    const float* wt = w2t + cc * 1600 + c2;   // weight (ky,kx) at wt[(ky*5+kx)*64]
    const float* pb = &pooled[cc * 144];
    float rows[2][12];
    *(float4*)&rows[0][0] = *(const float4*)&pb[r0 * 12];
    *(float4*)&rows[0][4] = *(const float4*)&pb[r0 * 12 + 4];
    *(float4*)&rows[0][8] = *(const float4*)&pb[r0 * 12 + 8];
    #pragma unroll
    for (int ky = 0; ky < 5; ky++) {
      float* B = rows[(ky + 1) & 1];
      const float* bp = &pb[(r0 + ky + 1) * 12];
      *(float4*)&B[0] = *(const float4*)&bp[0];
      *(float4*)&B[4] = *(const float4*)&bp[4];
      *(float4*)&B[8] = *(const float4*)&bp[8];
      const float* A = rows[ky & 1];
      #pragma unroll
      for (int kx = 0; kx < 5; kx++) {
        const float w = wt[(ky * 5 + kx) << 6];
        #pragma unroll
        for (int ox = 0; ox < 8; ox++) acc0[ox] = fmaf(A[ox + kx], w, acc0[ox]);
        #pragma unroll
        for (int ox = 0; ox < 8; ox++) acc1[ox] = fmaf(B[ox + kx], w, acc1[ox]);
      }
    }
  }

  float asum = 0.0f;
  #pragma unroll
  for (int i = 0; i < 8; i++) asum += fabsf(acc0[i]) + fabsf(acc1[i]);
  float tot = blockReduceSumF(asum, red, tid, 4);
  float delta = (0.7f * tot) / 4096.0f;

  float msum = 0.0f, mcnt = 0.0f;
  #pragma unroll
  for (int i = 0; i < 8; i++) {
    float f0 = fabsf(acc0[i]);
    if (f0 > delta) { msum += f0; mcnt += 1.0f; }
    float f1 = fabsf(acc1[i]);
    if (f1 > delta) { msum += f1; mcnt += 1.0f; }
  }
  float2 mm = blockReduceSum2F(msum, mcnt, red, tid, 4);
  if (tid == 0) alpha2[smp] = (mm.y > 0.0f) ? (mm.x / mm.y) : 0.0f;

  signed char* so = s2full + (size_t)smp * 4096 + c2 * 64 + r0 * 8;
  #pragma unroll
  for (int ox = 0; ox < 8; ox++) {
    float v = acc0[ox];
    so[ox] = (signed char)((v > delta) ? 1 : ((v < -delta) ? -1 : 0));
  }
  #pragma unroll
  for (int ox = 0; ox < 8; ox++) {
    float v = acc1[ox];
    so[8 + ox] = (signed char)((v > delta) ? 1 : ((v < -delta) ? -1 : 0));
  }
}

// ---------------- K0t: transpose fc1 weights into w1t[k][o] (into dead s1full) ----------
__global__ void k0_transpose(const float* __restrict__ w1f, float* __restrict__ w1t) {
  int i = blockIdx.x * 256 + threadIdx.x;  // i over 524288
  int k = i >> 9;
  int o = i & 511;
  w1t[i] = w1f[o * 1024 + k];
}

// ---------------- K3: 4 samples/block; fc1 via transposed weights — R13 verbatim ----
__global__ __launch_bounds__(1024, 4) void k3_fc(
    const signed char* __restrict__ s2full, const float* __restrict__ alpha2,
    const float* __restrict__ w1t, const float* __restrict__ f1b,
    const float* __restrict__ w2f, const float* __restrict__ f2b,
    const float* __restrict__ g2, const float* __restrict__ bt2,
    float* __restrict__ out) {
  __shared__ float S[16384];
  __shared__ float fco[4][512];
  __shared__ float g2l[64], bt2l[64];
  __shared__ float redm[4][4];
  __shared__ float out2[4][10];

  const int tid = threadIdx.x;
  const int blk = blockIdx.x;
  const float BNINV = (float)(1.0 / sqrt(1.0 + 1e-5));

  if (tid < 64) { g2l[tid] = g2[tid] * BNINV; bt2l[tid] = bt2[tid]; }
  __syncthreads();

  float* h4 = S;
  for (int e = tid; e < 4096; e += 1024) {
    int j = e >> 2;
    int s = e & 3;
    int cc = j >> 4;
    int r = j & 15;
    int py = r >> 2;
    int px = r & 3;
    const signed char* sp = s2full + (size_t)(blk * 4 + s) * 4096 + cc * 64 + (py * 2) * 8 + px * 2;
    float a2 = alpha2[blk * 4 + s];
    float m = -1e30f;
    #pragma unroll
    for (int dy = 0; dy < 2; dy++)
      #pragma unroll
      for (int dx = 0; dx < 2; dx++) {
        float v = ((float)sp[dy * 8 + dx] * a2) * g2l[cc] + bt2l[cc];
        m = (v > m) ? v : m;
      }
    h4[j * 4 + s] = (m > 0.0f) ? m : 0.0f;
  }
  __syncthreads();

  const int kp = tid >> 7;
  const int og = tid & 127;
  float a00=0,a01=0,a02=0,a03=0, a10=0,a11=0,a12=0,a13=0;
  float a20=0,a21=0,a22=0,a23=0, a30=0,a31=0,a32=0,a33=0;
  const float4* w4 = (const float4*)w1t;
  const float4* h44 = (const float4*)h4;
  const int kbase = kp << 7;
  for (int kk = 0; kk < 128; kk++) {
    const int k = kbase + kk;
    const float4 wv = w4[(k << 7) + og];
    const float4 hv = h44[k];
    a00 = fmaf(hv.x, wv.x, a00); a01 = fmaf(hv.y, wv.x, a01);
    a02 = fmaf(hv.z, wv.x, a02); a03 = fmaf(hv.w, wv.x, a03);
    a10 = fmaf(hv.x, wv.y, a10); a11 = fmaf(hv.y, wv.y, a11);
    a12 = fmaf(hv.z, wv.y, a12); a13 = fmaf(hv.w, wv.y, a13);
    a20 = fmaf(hv.x, wv.z, a20); a21 = fmaf(hv.y, wv.z, a21);
    a22 = fmaf(hv.z, wv.z, a22); a23 = fmaf(hv.w, wv.z, a23);
    a30 = fmaf(hv.x, wv.w, a30); a31 = fmaf(hv.y, wv.w, a31);
    a32 = fmaf(hv.z, wv.w, a32); a33 = fmaf(hv.w, wv.w, a33);
  }
  __syncthreads();
  {
    float4* p4 = (float4*)S;
    const int base = (kp << 9) + (og << 2);
    p4[base + 0] = make_float4(a00, a01, a02, a03);
    p4[base + 1] = make_float4(a10, a11, a12, a13);
    p4[base + 2] = make_float4(a20, a21, a22, a23);
    p4[base + 3] = make_float4(a30, a31, a32, a33);
  }
  __syncthreads();

  for (int p = tid; p < 2048; p += 1024) {
    int o = p >> 2;
    int s = p & 3;
    float v = S[p];
    #pragma unroll
    for (int kp2 = 1; kp2 < 8; kp2++) v += S[kp2 * 2048 + p];
    fco[s][o] = v + f1b[o];
  }
  __syncthreads();

  float (*h3)[512] = (float(*)[512])S;
  const int sg = tid >> 8;
  const int tj = tid & 255;
  float v0 = fco[sg][tj];
  float v1 = fco[sg][tj + 256];
  float av0 = fabsf(v0), av1 = fabsf(v1);
  float tot = groupReduce4w(av0 + av1, redm[sg], tj);
  float delta = (0.7f * tot) / 512.0f;
  float m0 = (av0 > delta) ? av0 : 0.0f;
  float m1 = (av1 > delta) ? av1 : 0.0f;
  float msum = groupReduce4w(m0 + m1, redm[sg], tj);
  float mcnt = groupReduce4w(((av0 > delta) ? 1.0f : 0.0f) + ((av1 > delta) ? 1.0f : 0.0f),
                             redm[sg], tj);
  float alpha3 = (mcnt > 0.0f) ? (msum / mcnt) : 0.0f;
  {
    float t0 = (v0 > delta) ? 1.0f : ((v0 < -delta) ? -1.0f : 0.0f);
    float hv0 = t0 * alpha3;
    h3[sg][tj] = (hv0 > 0.0f) ? hv0 : 0.0f;
    float t1 = (v1 > delta) ? 1.0f : ((v1 < -delta) ? -1.0f : 0.0f);
    float hv1 = t1 * alpha3;
    h3[sg][tj + 256] = (hv1 > 0.0f) ? hv1 : 0.0f;
  }
  __syncthreads();

  const int lane = tid & 63;
  const int wid = tid >> 6;
  for (int t = wid; t < 40; t += 16) {
    int s = t / 10;
    int o = t - s * 10;
    float acc = 0.0f;
    #pragma unroll
    for (int m = 0; m < 8; m++) {
      int j = lane + (m << 6);
      acc = fmaf(h3[s][j], w2f[o * 512 + j], acc);
    }
    #pragma unroll
    for (int off = 32; off > 0; off >>= 1) acc += __shfl_xor(acc, off);
    if (lane == 0) out2[s][o] = acc + f2b[o];
  }
  __syncthreads();

  if (tid < 4) {
    int s = tid;
    float t2 = 0.0f;
    for (int i = 0; i < 10; i++) t2 += fabsf(out2[s][i]);
    float d = (0.7f * t2) / 10.0f;
    float ms = 0.0f, mc = 0.0f;
    for (int i = 0; i < 10; i++) {
      float a = fabsf(out2[s][i]);
      if (a > d) { ms += a; mc += 1.0f; }
    }
    float al = (mc > 0.0f) ? (ms / mc) : 0.0f;
    for (int i = 0; i < 10; i++) {
      float vv = out2[s][i];
      float sv = (vv > d) ? 1.0f : ((vv < -d) ? -1.0f : 0.0f);
      out[(size_t)(blk * 4 + s) * 10 + i] = sv * al;
    }
  }
}

// assumption-violation marker
__global__ void k_marker(float* __restrict__ out, int n, float val) {
  int i = blockIdx.x * 256 + threadIdx.x;
  if (i < n) out[i] = val;
}

extern "C" void kernel_launch(void* const* d_in, const int* in_sizes, int n_in,
                              void* d_out, int out_size, void* d_ws, size_t ws_size,
                              hipStream_t stream) {
  float* out = (float*)d_out;

  static const int expect[13] = {1605632, 800, 32, 32, 32, 51200, 64, 64, 64,
                                 524288, 512, 5120, 10};
  float marker = 0.0f;
  if (n_in != 13) marker = 304.0f;
  else {
    for (int i = 0; i < 13; i++)
      if (in_sizes[i] != expect[i]) { marker = 320.0f + 16.0f * i; break; }
  }
  if (marker == 0.0f && out_size != 20480) marker = 560.0f;

  float* alpha1 = (float*)d_ws;                           // 2048
  float* alpha2 = alpha1 + BATCH;                         // 2048
  float* w2t    = alpha2 + BATCH;                         // 51200 (200 KB)
  signed char* s1full = (signed char*)(w2t + 51200);      // 2048*18432 (dead after k2;
                                                          //  first 2MB reused as w1t)
  signed char* s2full = s1full + (size_t)BATCH * 18432;   // 2048*4096
  size_t needed = (size_t)((s2full + (size_t)BATCH * 4096) - (signed char*)d_ws);
  if (marker == 0.0f && ws_size < needed) marker = 576.0f;

  if (marker != 0.0f) {
    k_marker<<<dim3((out_size + 255) / 256), dim3(256), 0, stream>>>(out, out_size, marker);
    return;
  }

  const float* x   = (const float*)d_in[0];
  const float* c1w = (const float*)d_in[1];
  const float* c1b = (const float*)d_in[2];
  const float* g1  = (const float*)d_in[3];
  const float* bt1 = (const float*)d_in[4];
  const float* c2w = (const float*)d_in[5];
  const float* c2b = (const float*)d_in[6];
  const float* g2  = (const float*)d_in[7];
  const float* bt2 = (const float*)d_in[8];
  const float* f1w = (const float*)d_in[9];
  const float* f1b = (const float*)d_in[10];
  const float* f2w = (const float*)d_in[11];
  const float* f2b = (const float*)d_in[12];

  float* w1t = (float*)s1full;

  k0_w2t<<<dim3(200), dim3(256), 0, stream>>>(c2w, w2t);
  k1_conv1<<<dim3(BATCH), dim3(512), 0, stream>>>(x, c1w, c1b, s1full, alpha1);
  k2_conv2<<<dim3(BATCH), dim3(256), 0, stream>>>(s1full, alpha1, w2t, c2b, g1, bt1, s2full, alpha2);
  k0_transpose<<<dim3(2048), dim3(256), 0, stream>>>(f1w, w1t);
  k3_fc<<<dim3(BATCH / 4), dim3(1024), 0, stream>>>(s2full, alpha2, w1t, f1b, f2w, f2b, g2, bt2, out);
}